// Round 3
// baseline (7047.115 us; speedup 1.0000x reference)
//
#include <hip/hip_runtime.h>
#include <math.h>

#define BATCH   512
#define N       128
#define DDIM    1024
#define NITER   30
#define SIGMA_C 0.1f
#define EPS_C   1e-6f

#define PSTR    20            // forward panel row stride (floats): 16B-aligned, odd quad count -> bank spread
#define PELEMS  (130 * PSTR)  // 2600 floats per buffer (>= 16*132 backward staging)
#define BSTR    132           // backward staging row stride (floats)
#define MPAD    132           // gram kernel staging stride

// ---------------- Kernel A: Q = 2*(X X^T + eps I) ----------------
__global__ __launch_bounds__(256) void gram_kernel(const float* __restrict__ X,
                                                   float* __restrict__ Q) {
    const int b = blockIdx.x;
    const float* Xb = X + (size_t)b * N * DDIM;
    float* Qb = Q + (size_t)b * N * N;

    __shared__ float Xs[16][MPAD];
    const int t  = threadIdx.x;
    const int tx = t & 15, ty = t >> 4;
    const int li = t >> 1;
    const int lk = (t & 1) * 8;

    float acc[8][8];
#pragma unroll
    for (int u = 0; u < 8; ++u)
#pragma unroll
        for (int v = 0; v < 8; ++v) acc[u][v] = 0.0f;

    for (int k0 = 0; k0 < DDIM; k0 += 16) {
        const float4 p0 = *(const float4*)(Xb + (size_t)li * DDIM + k0 + lk);
        const float4 p1 = *(const float4*)(Xb + (size_t)li * DDIM + k0 + lk + 4);
        __syncthreads();
        Xs[lk + 0][li] = p0.x; Xs[lk + 1][li] = p0.y;
        Xs[lk + 2][li] = p0.z; Xs[lk + 3][li] = p0.w;
        Xs[lk + 4][li] = p1.x; Xs[lk + 5][li] = p1.y;
        Xs[lk + 6][li] = p1.z; Xs[lk + 7][li] = p1.w;
        __syncthreads();
#pragma unroll
        for (int kk = 0; kk < 16; ++kk) {
            float4 A0 = *(const float4*)&Xs[kk][ty * 8];
            float4 A1 = *(const float4*)&Xs[kk][ty * 8 + 4];
            float4 C0 = *(const float4*)&Xs[kk][tx * 8];
            float4 C1 = *(const float4*)&Xs[kk][tx * 8 + 4];
            float a[8] = {A0.x, A0.y, A0.z, A0.w, A1.x, A1.y, A1.z, A1.w};
            float c[8] = {C0.x, C0.y, C0.z, C0.w, C1.x, C1.y, C1.z, C1.w};
#pragma unroll
            for (int u = 0; u < 8; ++u)
#pragma unroll
                for (int v = 0; v < 8; ++v) acc[u][v] += a[u] * c[v];
        }
    }
#pragma unroll
    for (int u = 0; u < 8; ++u) {
        const int i = ty * 8 + u;
#pragma unroll
        for (int v = 0; v < 8; ++v) {
            const int k = tx * 8 + v;
            acc[u][v] = 2.0f * acc[u][v] + ((i == k) ? 2.0f * EPS_C : 0.0f);
        }
        float4 o0, o1;
        o0.x = acc[u][0]; o0.y = acc[u][1]; o0.z = acc[u][2]; o0.w = acc[u][3];
        o1.x = acc[u][4]; o1.y = acc[u][5]; o1.z = acc[u][6]; o1.w = acc[u][7];
        *(float4*)(Qb + (size_t)i * N + tx * 8)     = o0;
        *(float4*)(Qb + (size_t)i * N + tx * 8 + 4) = o1;
    }
}

// 16-term dot of two 16-float fragments
__device__ __forceinline__ float dot16(const float4& A0, const float4& A1,
                                       const float4& A2, const float4& A3,
                                       const float4& B0, const float4& B1,
                                       const float4& B2, const float4& B3) {
    float acc = A0.x * B0.x;
    acc = fmaf(A0.y, B0.y, acc); acc = fmaf(A0.z, B0.z, acc); acc = fmaf(A0.w, B0.w, acc);
    acc = fmaf(A1.x, B1.x, acc); acc = fmaf(A1.y, B1.y, acc);
    acc = fmaf(A1.z, B1.z, acc); acc = fmaf(A1.w, B1.w, acc);
    acc = fmaf(A2.x, B2.x, acc); acc = fmaf(A2.y, B2.y, acc);
    acc = fmaf(A2.z, B2.z, acc); acc = fmaf(A2.w, B2.w, acc);
    acc = fmaf(A3.x, B3.x, acc); acc = fmaf(A3.y, B3.y, acc);
    acc = fmaf(A3.z, B3.z, acc); acc = fmaf(A3.w, B3.w, acc);
    return acc;
}

// ---------------- Kernel B: primal-dual IPM, register-resident rows ----------------
// thread t: h = t>>7 (column half: cols 64h..64h+63), i = t&127 (row).
// Each thread holds its half-row in 16 float4 registers. LDS holds only the
// current NB=16 panel (double-buffered) + small vectors. RHS vectors ride as
// augmented rows 128/129 of the panel (forward substitution fused).
__global__ __launch_bounds__(256, 4) void ipm_kernel(const float* __restrict__ Q,
                                                     float* __restrict__ alphas) {
    const int b = blockIdx.x;
    const float* Qb = Q + (size_t)b * N * N;

    __shared__ __align__(16) float P[2][PELEMS];
    __shared__ __align__(16) float av[N], lamv[N], Pp[N], dinv[N], v0[N], v1[N];
    __shared__ __align__(16) float part[256];
    __shared__ float scal[8];   // 0:nu 1:mu 2:r_pri 3:dnu 4:t_step

    const int t = threadIdx.x;
    const int h = t >> 7;
    const int i = t & 127;
    const int lane = t & 63;
    const int wave = t >> 6;

    if (t < N) {
        av[t]   = 1.0f / (float)N;
        lamv[t] = 1.0f;
        Pp[t]   = -0.5f * Qb[(size_t)t * N + t];
    }
    if (t == 0) scal[0] = 0.0f;
    __syncthreads();

    const float* Qrow = Qb + (size_t)i * N + 64 * h;

#pragma unroll 1
    for (int iter = 0; iter < NITER; ++iter) {
        // ---- load Q half-row into registers; qa partial ----
        float4 R[16];
#pragma unroll
        for (int s = 0; s < 16; ++s) R[s] = *(const float4*)(Qrow + 4 * s);
        {
            float qs = 0.0f;
#pragma unroll
            for (int s = 0; s < 16; ++s) {
                const float4 a4 = *(const float4*)&av[64 * h + 4 * s];
                qs = fmaf(R[s].x, a4.x, qs); qs = fmaf(R[s].y, a4.y, qs);
                qs = fmaf(R[s].z, a4.z, qs); qs = fmaf(R[s].w, a4.w, qs);
            }
            part[t] = qs;
        }
        if (wave == 0) {           // r_pri, mu
            float sa  = av[lane] + av[lane + 64];
            float sal = av[lane] * lamv[lane] + av[lane + 64] * lamv[lane + 64];
#pragma unroll
            for (int o = 32; o; o >>= 1) { sa += __shfl_xor(sa, o); sal += __shfl_xor(sal, o); }
            if (lane == 0) { scal[2] = sa - 1.0f; scal[1] = sal / (float)N; }
        }
        __syncthreads();                                   // B1
        const float mu = scal[1];
        const float nu = scal[0];
        if (t < N) {
            const float ai = av[t];
            const float qv = part[t] + part[t + 128];
            v0[t] = -(qv + Pp[t] + nu - SIGMA_C * mu / ai);
            v1[t] = 1.0f;
        }
        {   // diag shift into registers (predicated sweep, static indexing)
            const float dadd = lamv[i] / av[i];
#pragma unroll
            for (int s = 0; s < 16; ++s) {
                const int jc = 64 * h + 4 * s;
                R[s].x += (jc + 0 == i) ? dadd : 0.0f;
                R[s].y += (jc + 1 == i) ? dadd : 0.0f;
                R[s].z += (jc + 2 == i) ? dadd : 0.0f;
                R[s].w += (jc + 3 == i) ? dadd : 0.0f;
            }
        }
        __syncthreads();                                   // B2

        // ============== forward: blocked Cholesky over 8 panels ==============
#pragma unroll 1
        for (int jb = 0; jb < 8; ++jb) {
            const int j0 = 16 * jb;
            float* Pb = P[jb & 1];
            // --- stage panel cols from registers ---
            if (h == (jb >> 2) && i >= j0) {
                float4* dst = (float4*)&Pb[(i - j0) * PSTR];
                switch (jb & 3) {
                    case 0:  dst[0] = R[0];  dst[1] = R[1];  dst[2] = R[2];  dst[3] = R[3];  break;
                    case 1:  dst[0] = R[4];  dst[1] = R[5];  dst[2] = R[6];  dst[3] = R[7];  break;
                    case 2:  dst[0] = R[8];  dst[1] = R[9];  dst[2] = R[10]; dst[3] = R[11]; break;
                    default: dst[0] = R[12]; dst[1] = R[13]; dst[2] = R[14]; dst[3] = R[15]; break;
                }
            }
            if (jb == 0 && t < 8) {   // initial RHS rows
                const int rr = t >> 2;
                const int c4 = (t & 3) * 4;
                const float* src = rr ? v1 : v0;
                *(float4*)&Pb[(128 + rr) * PSTR + c4] = *(const float4*)&src[c4];
            }
            __syncthreads();                               // B3
            // --- diag block factor: wave 0, register + shfl ---
            if (wave == 0) {
                const int r = lane;
                float row[16];
                float myri = 0.0f;
                if (r < 16) {
#pragma unroll
                    for (int c = 0; c < 16; ++c) row[c] = Pb[r * PSTR + c];
                } else {
#pragma unroll
                    for (int c = 0; c < 16; ++c) row[c] = 1.0f;
                }
#pragma unroll
                for (int c = 0; c < 16; ++c) {
                    const float d  = __shfl(row[c], c);
                    const float ri = rsqrtf(d);
                    if (r == c) { row[c] = d * ri; myri = ri; }
                    const float lv = (r > c && r < 16) ? row[c] * ri : 0.0f;
                    if (r > c && r < 16) row[c] = lv;
#pragma unroll
                    for (int k = c + 1; k < 16; ++k) {
                        const float lk = __shfl(lv, k);
                        row[k] -= lv * lk;
                    }
                }
                if (r < 16) {
#pragma unroll
                    for (int c = 0; c < 16; ++c) Pb[r * PSTR + c] = row[c];
                    dinv[j0 + r] = myri;
                }
            }
            __syncthreads();                               // B4
            // --- panel solve: one thread per row (incl. 2 RHS rows) ---
            {
                const int nsolve = N - 16 - j0;
                if (t < nsolve + 2) {
                    const int rp = (t < nsolve) ? (16 + t) : (128 + (t - nsolve));
                    float* prow = &Pb[rp * PSTR];
                    float w[16];
#pragma unroll
                    for (int c = 0; c < 16; ++c) w[c] = prow[c];
#pragma unroll
                    for (int c = 0; c < 16; ++c) {
                        float s = w[c];
#pragma unroll
                        for (int m = 0; m < c; ++m) s -= w[m] * Pb[c * PSTR + m];
                        w[c] = s * dinv[j0 + c];
                    }
#pragma unroll
                    for (int c = 0; c < 16; ++c) prow[c] = w[c];
                }
            }
            __syncthreads();                               // B5
            // --- readback solved panel into registers ---
            if (h == (jb >> 2) && i >= j0) {
                const float4* src = (const float4*)&Pb[(i - j0) * PSTR];
                switch (jb & 3) {
                    case 0:  R[0]  = src[0]; R[1]  = src[1]; R[2]  = src[2]; R[3]  = src[3]; break;
                    case 1:  R[4]  = src[0]; R[5]  = src[1]; R[6]  = src[2]; R[7]  = src[3]; break;
                    case 2:  R[8]  = src[0]; R[9]  = src[1]; R[10] = src[2]; R[11] = src[3]; break;
                    default: R[12] = src[0]; R[13] = src[1]; R[14] = src[2]; R[15] = src[3]; break;
                }
            }
            // --- trailing update on register rows (waves 0,1,3) ---
            const int maxi = (wave & 1) ? 127 : 63;
            const bool isW2 = (h == 1) && ((wave & 1) == 0);   // wave 2: no trailing ever
            if (!isW2 && maxi >= j0 + 16) {
                const int ra = (i > j0) ? (i - j0) : 0;
                const float4* Ar = (const float4*)&Pb[ra * PSTR];
                const float4 A0 = Ar[0], A1 = Ar[1], A2 = Ar[2], A3 = Ar[3];
#pragma unroll
                for (int s = 0; s < 16; ++s) {
                    float sub0, sub1, sub2, sub3;
#pragma unroll
                    for (int c = 0; c < 4; ++c) {
                        const int j  = 64 * h + 4 * s + c;
                        const int rb = (j > j0) ? (j - j0) : 0;
                        const float4* Br = (const float4*)&Pb[rb * PSTR];
                        const float acc = dot16(A0, A1, A2, A3, Br[0], Br[1], Br[2], Br[3]);
                        const bool act = (j >= j0 + 16) && (j <= i);
                        const float sv = act ? acc : 0.0f;
                        if (c == 0) sub0 = sv; else if (c == 1) sub1 = sv;
                        else if (c == 2) sub2 = sv; else sub3 = sv;
                    }
                    R[s].x -= sub0; R[s].y -= sub1; R[s].z -= sub2; R[s].w -= sub3;
                }
            }
            // --- wave 2: RHS trailing + copyback + next-panel RHS stage ---
            if (isW2) {
                const int k  = lane;
                const int rr = k & 1;
                float* vv = rr ? v1 : v0;
                const float4* Yr = (const float4*)&Pb[(128 + rr) * PSTR];
                const float4 Y0 = Yr[0], Y1 = Yr[1], Y2 = Yr[2], Y3 = Yr[3];
#pragma unroll
                for (int c = 0; c < 4; ++c) {
                    const int j = (k >> 1) * 4 + c;
                    if (j >= j0 + 16) {
                        const float4* Br = (const float4*)&Pb[(j - j0) * PSTR];
                        vv[j] -= dot16(Y0, Y1, Y2, Y3, Br[0], Br[1], Br[2], Br[3]);
                    } else if (j >= j0) {
                        vv[j] = Pb[(128 + rr) * PSTR + (j - j0)];  // solved y copyback
                    }
                }
                if (jb < 7) {
                    float* Pn = P[(jb + 1) & 1];
#pragma unroll
                    for (int c = 0; c < 4; ++c) {
                        const int j = (k >> 1) * 4 + c;
                        if (j >= j0 + 16 && j < j0 + 32)
                            Pn[(128 + rr) * PSTR + (j - j0 - 16)] = vv[j];
                    }
                }
            }
        }
        __syncthreads();                                   // B6
        // ============== backward solve (L^T x = y) on wave 0 ==============
        float b00 = 0.0f, b01 = 0.0f, b10 = 0.0f, b11 = 0.0f;
        if (wave == 0) {
            b00 = v0[lane]; b01 = v0[lane + 64];
            b10 = v1[lane]; b11 = v1[lane + 64];
        }
#pragma unroll 1
        for (int jb = 7; jb >= 0; --jb) {
            const int j0 = 16 * jb;
            float* Pb = P[jb & 1];
            if (i >= j0 && i < j0 + 16) {   // stage 16 L-rows (both halves)
                float4* dst = (float4*)&Pb[(i - j0) * BSTR + 64 * h];
#pragma unroll
                for (int s = 0; s < 16; ++s) dst[s] = R[s];
            }
            __syncthreads();                               // B7
            if (wave == 0) {
#pragma unroll
                for (int c2 = 15; c2 >= 0; --c2) {
                    const int c = j0 + c2;
                    const float di = dinv[c];
                    const float s0 = (c < 64) ? b00 : b01;
                    const float s1 = (c < 64) ? b10 : b11;
                    const float x0 = __shfl(s0, c & 63) * di;
                    const float x1 = __shfl(s1, c & 63) * di;
                    const float L0 = Pb[c2 * BSTR + lane];
                    const float L1 = Pb[c2 * BSTR + lane + 64];
                    const int r0 = lane, r1 = lane + 64;
                    if (r0 < c)       { b00 -= L0 * x0; b10 -= L0 * x1; }
                    else if (r0 == c) { b00 = x0;       b10 = x1; }
                    if (r1 < c)       { b01 -= L1 * x0; b11 -= L1 * x1; }
                    else if (r1 == c) { b01 = x0;       b11 = x1; }
                }
            }
        }
        // ---- dnu + step size on wave 0 ----
        if (wave == 0) {
            v0[lane] = b00; v0[lane + 64] = b01;
            v1[lane] = b10; v1[lane + 64] = b11;
            float s0 = b00 + b01, s1 = b10 + b11;
#pragma unroll
            for (int o = 32; o; o >>= 1) { s0 += __shfl_xor(s0, o); s1 += __shfl_xor(s1, o); }
            const float dnu = (s0 + scal[2]) / s1;
            float r = 3.4e38f;
            const float a0 = av[lane], a1 = av[lane + 64];
            const float lm0 = lamv[lane], lm1 = lamv[lane + 64];
            const float da0 = b00 - dnu * b10;
            const float da1 = b01 - dnu * b11;
            const float dl0 = -lm0 + SIGMA_C * mu / a0 - lm0 * da0 / a0;
            const float dl1 = -lm1 + SIGMA_C * mu / a1 - lm1 * da1 / a1;
            if (da0 < 0.0f) r = fminf(r, -a0 / da0);
            if (da1 < 0.0f) r = fminf(r, -a1 / da1);
            if (dl0 < 0.0f) r = fminf(r, -lm0 / dl0);
            if (dl1 < 0.0f) r = fminf(r, -lm1 / dl1);
#pragma unroll
            for (int o = 32; o; o >>= 1) r = fminf(r, __shfl_xor(r, o));
            if (lane == 0) { scal[3] = dnu; scal[4] = fminf(1.0f, 0.99f * r); }
        }
        __syncthreads();                                   // B8
        // ---- update ----
        {
            const float ts   = scal[4];
            const float dnu2 = scal[3];
            if (t < N) {
                const float ai = av[t], li = lamv[t];
                const float dai = v0[t] - dnu2 * v1[t];
                const float dli = -li + SIGMA_C * mu / ai - li * dai / ai;
                av[t]   = ai + ts * dai;
                lamv[t] = li + ts * dli;
            }
            if (t == 0) scal[0] = nu + ts * dnu2;
        }
        __syncthreads();                                   // B9
    }

    if (t < N) alphas[(size_t)b * N + t] = av[t];
}

// ---------------- Kernel C: centers = alpha^T X ----------------
__global__ __launch_bounds__(256) void centers_kernel(const float* __restrict__ X,
                                                      const float* __restrict__ alphas,
                                                      float* __restrict__ out) {
    const int b = blockIdx.x;
    __shared__ float al[N];
    const int t = threadIdx.x;
    if (t < N) al[t] = alphas[(size_t)b * N + t];
    __syncthreads();
    const float* Xb = X + (size_t)b * N * DDIM;
    float acc0 = 0.0f, acc1 = 0.0f, acc2 = 0.0f, acc3 = 0.0f;
    for (int s = 0; s < N; ++s) {
        const float a = al[s];
        const float* row = Xb + (size_t)s * DDIM + t;
        acc0 += a * row[0];
        acc1 += a * row[256];
        acc2 += a * row[512];
        acc3 += a * row[768];
    }
    float* ob = out + (size_t)b * DDIM + t;
    ob[0]   = acc0;
    ob[256] = acc1;
    ob[512] = acc2;
    ob[768] = acc3;
}

extern "C" void kernel_launch(void* const* d_in, const int* in_sizes, int n_in,
                              void* d_out, int out_size, void* d_ws, size_t ws_size,
                              hipStream_t stream) {
    (void)in_sizes; (void)n_in; (void)out_size; (void)ws_size;
    const float* X = (const float*)d_in[0];
    float* out = (float*)d_out;
    float* Q = (float*)d_ws;                       // 512*128*128 f32 = 32 MB
    float* alphas = Q + (size_t)BATCH * N * N;     // + 256 KB
    gram_kernel<<<dim3(BATCH), dim3(256), 0, stream>>>(X, Q);
    ipm_kernel<<<dim3(BATCH), dim3(256), 0, stream>>>(Q, alphas);
    centers_kernel<<<dim3(BATCH), dim3(256), 0, stream>>>(X, alphas, out);
}

// Round 4
// 5606.215 us; speedup vs baseline: 1.2570x; 1.2570x over previous
//
#include <hip/hip_runtime.h>
#include <math.h>

#define BATCH   512
#define N       128
#define DDIM    1024
#define NITER   30
#define SIGMA_C 0.1f
#define EPS_C   1e-6f

#define PSTR    20            // forward panel row stride (floats): 16B-aligned, odd quad count -> bank spread
#define PELEMS  (130 * PSTR)  // 2600 floats per buffer (>= 16*132 backward staging)
#define BSTR    132           // backward staging row stride (floats)
#define MPAD    132           // gram kernel staging stride

// ---------------- Kernel A: Q = 2*(X X^T + eps I) ----------------
__global__ __launch_bounds__(256) void gram_kernel(const float* __restrict__ X,
                                                   float* __restrict__ Q) {
    const int b = blockIdx.x;
    const float* Xb = X + (size_t)b * N * DDIM;
    float* Qb = Q + (size_t)b * N * N;

    __shared__ float Xs[16][MPAD];
    const int t  = threadIdx.x;
    const int tx = t & 15, ty = t >> 4;
    const int li = t >> 1;
    const int lk = (t & 1) * 8;

    float acc[8][8];
#pragma unroll
    for (int u = 0; u < 8; ++u)
#pragma unroll
        for (int v = 0; v < 8; ++v) acc[u][v] = 0.0f;

    for (int k0 = 0; k0 < DDIM; k0 += 16) {
        const float4 p0 = *(const float4*)(Xb + (size_t)li * DDIM + k0 + lk);
        const float4 p1 = *(const float4*)(Xb + (size_t)li * DDIM + k0 + lk + 4);
        __syncthreads();
        Xs[lk + 0][li] = p0.x; Xs[lk + 1][li] = p0.y;
        Xs[lk + 2][li] = p0.z; Xs[lk + 3][li] = p0.w;
        Xs[lk + 4][li] = p1.x; Xs[lk + 5][li] = p1.y;
        Xs[lk + 6][li] = p1.z; Xs[lk + 7][li] = p1.w;
        __syncthreads();
#pragma unroll
        for (int kk = 0; kk < 16; ++kk) {
            float4 A0 = *(const float4*)&Xs[kk][ty * 8];
            float4 A1 = *(const float4*)&Xs[kk][ty * 8 + 4];
            float4 C0 = *(const float4*)&Xs[kk][tx * 8];
            float4 C1 = *(const float4*)&Xs[kk][tx * 8 + 4];
            float a[8] = {A0.x, A0.y, A0.z, A0.w, A1.x, A1.y, A1.z, A1.w};
            float c[8] = {C0.x, C0.y, C0.z, C0.w, C1.x, C1.y, C1.z, C1.w};
#pragma unroll
            for (int u = 0; u < 8; ++u)
#pragma unroll
                for (int v = 0; v < 8; ++v) acc[u][v] += a[u] * c[v];
        }
    }
#pragma unroll
    for (int u = 0; u < 8; ++u) {
        const int i = ty * 8 + u;
#pragma unroll
        for (int v = 0; v < 8; ++v) {
            const int k = tx * 8 + v;
            acc[u][v] = 2.0f * acc[u][v] + ((i == k) ? 2.0f * EPS_C : 0.0f);
        }
        float4 o0, o1;
        o0.x = acc[u][0]; o0.y = acc[u][1]; o0.z = acc[u][2]; o0.w = acc[u][3];
        o1.x = acc[u][4]; o1.y = acc[u][5]; o1.z = acc[u][6]; o1.w = acc[u][7];
        *(float4*)(Qb + (size_t)i * N + tx * 8)     = o0;
        *(float4*)(Qb + (size_t)i * N + tx * 8 + 4) = o1;
    }
}

// 16-term dot of two 16-float fragments
__device__ __forceinline__ float dot16(const float4& A0, const float4& A1,
                                       const float4& A2, const float4& A3,
                                       const float4& B0, const float4& B1,
                                       const float4& B2, const float4& B3) {
    float acc = A0.x * B0.x;
    acc = fmaf(A0.y, B0.y, acc); acc = fmaf(A0.z, B0.z, acc); acc = fmaf(A0.w, B0.w, acc);
    acc = fmaf(A1.x, B1.x, acc); acc = fmaf(A1.y, B1.y, acc);
    acc = fmaf(A1.z, B1.z, acc); acc = fmaf(A1.w, B1.w, acc);
    acc = fmaf(A2.x, B2.x, acc); acc = fmaf(A2.y, B2.y, acc);
    acc = fmaf(A2.z, B2.z, acc); acc = fmaf(A2.w, B2.w, acc);
    acc = fmaf(A3.x, B3.x, acc); acc = fmaf(A3.y, B3.y, acc);
    acc = fmaf(A3.z, B3.z, acc); acc = fmaf(A3.w, B3.w, acc);
    return acc;
}

// ---------------- Kernel B: primal-dual IPM, register-resident rows ----------------
// thread t: h = t>>7 (column half: cols 64h..64h+63), i = t&127 (row).
// Each thread holds its half-row in 16 float4 registers. LDS holds only the
// current NB=16 panel (double-buffered) + small vectors. RHS vectors ride as
// augmented rows 128/129 of the panel (forward substitution fused).
// NOTE: no min-waves clamp -- __launch_bounds__(256,4) capped VGPR at 64 and
// spilled the entire R[16] array to scratch (7 GB/dispatch HBM traffic).
__global__ __launch_bounds__(256) void ipm_kernel(const float* __restrict__ Q,
                                                  float* __restrict__ alphas) {
    const int b = blockIdx.x;
    const float* Qb = Q + (size_t)b * N * N;

    __shared__ __align__(16) float P[2][PELEMS];
    __shared__ __align__(16) float av[N], lamv[N], Pp[N], dinv[N], v0[N], v1[N];
    __shared__ __align__(16) float part[256];
    __shared__ float scal[8];   // 0:nu 1:mu 2:r_pri 3:dnu 4:t_step

    const int t = threadIdx.x;
    const int h = t >> 7;
    const int i = t & 127;
    const int lane = t & 63;
    const int wave = t >> 6;

    if (t < N) {
        av[t]   = 1.0f / (float)N;
        lamv[t] = 1.0f;
        Pp[t]   = -0.5f * Qb[(size_t)t * N + t];
    }
    if (t == 0) scal[0] = 0.0f;
    __syncthreads();

    const float* Qrow = Qb + (size_t)i * N + 64 * h;

#pragma unroll 1
    for (int iter = 0; iter < NITER; ++iter) {
        // ---- load Q half-row into registers; qa partial ----
        float4 R[16];
#pragma unroll
        for (int s = 0; s < 16; ++s) R[s] = *(const float4*)(Qrow + 4 * s);
        {
            float qs = 0.0f;
#pragma unroll
            for (int s = 0; s < 16; ++s) {
                const float4 a4 = *(const float4*)&av[64 * h + 4 * s];
                qs = fmaf(R[s].x, a4.x, qs); qs = fmaf(R[s].y, a4.y, qs);
                qs = fmaf(R[s].z, a4.z, qs); qs = fmaf(R[s].w, a4.w, qs);
            }
            part[t] = qs;
        }
        if (wave == 0) {           // r_pri, mu
            float sa  = av[lane] + av[lane + 64];
            float sal = av[lane] * lamv[lane] + av[lane + 64] * lamv[lane + 64];
#pragma unroll
            for (int o = 32; o; o >>= 1) { sa += __shfl_xor(sa, o); sal += __shfl_xor(sal, o); }
            if (lane == 0) { scal[2] = sa - 1.0f; scal[1] = sal / (float)N; }
        }
        __syncthreads();                                   // B1
        const float mu = scal[1];
        const float nu = scal[0];
        if (t < N) {
            const float ai = av[t];
            const float qv = part[t] + part[t + 128];
            v0[t] = -(qv + Pp[t] + nu - SIGMA_C * mu / ai);
            v1[t] = 1.0f;
        }
        {   // diag shift into registers (predicated sweep, static indexing)
            const float dadd = lamv[i] / av[i];
#pragma unroll
            for (int s = 0; s < 16; ++s) {
                const int jc = 64 * h + 4 * s;
                R[s].x += (jc + 0 == i) ? dadd : 0.0f;
                R[s].y += (jc + 1 == i) ? dadd : 0.0f;
                R[s].z += (jc + 2 == i) ? dadd : 0.0f;
                R[s].w += (jc + 3 == i) ? dadd : 0.0f;
            }
        }
        __syncthreads();                                   // B2

        // ============== forward: blocked Cholesky over 8 panels ==============
#pragma unroll 1
        for (int jb = 0; jb < 8; ++jb) {
            const int j0 = 16 * jb;
            float* Pb = P[jb & 1];
            // --- stage panel cols from registers ---
            if (h == (jb >> 2) && i >= j0) {
                float4* dst = (float4*)&Pb[(i - j0) * PSTR];
                switch (jb & 3) {
                    case 0:  dst[0] = R[0];  dst[1] = R[1];  dst[2] = R[2];  dst[3] = R[3];  break;
                    case 1:  dst[0] = R[4];  dst[1] = R[5];  dst[2] = R[6];  dst[3] = R[7];  break;
                    case 2:  dst[0] = R[8];  dst[1] = R[9];  dst[2] = R[10]; dst[3] = R[11]; break;
                    default: dst[0] = R[12]; dst[1] = R[13]; dst[2] = R[14]; dst[3] = R[15]; break;
                }
            }
            if (jb == 0 && t < 8) {   // initial RHS rows
                const int rr = t >> 2;
                const int c4 = (t & 3) * 4;
                const float* src = rr ? v1 : v0;
                *(float4*)&Pb[(128 + rr) * PSTR + c4] = *(const float4*)&src[c4];
            }
            __syncthreads();                               // B3
            // --- diag block factor: wave 0, register + shfl ---
            if (wave == 0) {
                const int r = lane;
                float row[16];
                float myri = 0.0f;
                if (r < 16) {
#pragma unroll
                    for (int c = 0; c < 16; ++c) row[c] = Pb[r * PSTR + c];
                } else {
#pragma unroll
                    for (int c = 0; c < 16; ++c) row[c] = 1.0f;
                }
#pragma unroll
                for (int c = 0; c < 16; ++c) {
                    const float d  = __shfl(row[c], c);
                    const float ri = rsqrtf(d);
                    if (r == c) { row[c] = d * ri; myri = ri; }
                    const float lv = (r > c && r < 16) ? row[c] * ri : 0.0f;
                    if (r > c && r < 16) row[c] = lv;
#pragma unroll
                    for (int k = c + 1; k < 16; ++k) {
                        const float lk = __shfl(lv, k);
                        row[k] -= lv * lk;
                    }
                }
                if (r < 16) {
#pragma unroll
                    for (int c = 0; c < 16; ++c) Pb[r * PSTR + c] = row[c];
                    dinv[j0 + r] = myri;
                }
            }
            __syncthreads();                               // B4
            // --- panel solve: one thread per row (incl. 2 RHS rows) ---
            {
                const int nsolve = N - 16 - j0;
                if (t < nsolve + 2) {
                    const int rp = (t < nsolve) ? (16 + t) : (128 + (t - nsolve));
                    float* prow = &Pb[rp * PSTR];
                    float w[16];
#pragma unroll
                    for (int c = 0; c < 16; ++c) w[c] = prow[c];
#pragma unroll
                    for (int c = 0; c < 16; ++c) {
                        float s = w[c];
#pragma unroll
                        for (int m = 0; m < c; ++m) s -= w[m] * Pb[c * PSTR + m];
                        w[c] = s * dinv[j0 + c];
                    }
#pragma unroll
                    for (int c = 0; c < 16; ++c) prow[c] = w[c];
                }
            }
            __syncthreads();                               // B5
            // --- readback solved panel into registers ---
            if (h == (jb >> 2) && i >= j0) {
                const float4* src = (const float4*)&Pb[(i - j0) * PSTR];
                switch (jb & 3) {
                    case 0:  R[0]  = src[0]; R[1]  = src[1]; R[2]  = src[2]; R[3]  = src[3]; break;
                    case 1:  R[4]  = src[0]; R[5]  = src[1]; R[6]  = src[2]; R[7]  = src[3]; break;
                    case 2:  R[8]  = src[0]; R[9]  = src[1]; R[10] = src[2]; R[11] = src[3]; break;
                    default: R[12] = src[0]; R[13] = src[1]; R[14] = src[2]; R[15] = src[3]; break;
                }
            }
            // --- trailing update on register rows (waves 0,1,3) ---
            const int maxi = (wave & 1) ? 127 : 63;
            const bool isW2 = (h == 1) && ((wave & 1) == 0);   // wave 2: no trailing ever
            if (!isW2 && maxi >= j0 + 16) {
                const int ra = (i > j0) ? (i - j0) : 0;
                const float4* Ar = (const float4*)&Pb[ra * PSTR];
                const float4 A0 = Ar[0], A1 = Ar[1], A2 = Ar[2], A3 = Ar[3];
#pragma unroll
                for (int s = 0; s < 16; ++s) {
                    float sub0, sub1, sub2, sub3;
#pragma unroll
                    for (int c = 0; c < 4; ++c) {
                        const int j  = 64 * h + 4 * s + c;
                        const int rb = (j > j0) ? (j - j0) : 0;
                        const float4* Br = (const float4*)&Pb[rb * PSTR];
                        const float acc = dot16(A0, A1, A2, A3, Br[0], Br[1], Br[2], Br[3]);
                        const bool act = (j >= j0 + 16) && (j <= i);
                        const float sv = act ? acc : 0.0f;
                        if (c == 0) sub0 = sv; else if (c == 1) sub1 = sv;
                        else if (c == 2) sub2 = sv; else sub3 = sv;
                    }
                    R[s].x -= sub0; R[s].y -= sub1; R[s].z -= sub2; R[s].w -= sub3;
                }
            }
            // --- wave 2: RHS trailing + copyback + next-panel RHS stage ---
            if (isW2) {
                const int k  = lane;
                const int rr = k & 1;
                float* vv = rr ? v1 : v0;
                const float4* Yr = (const float4*)&Pb[(128 + rr) * PSTR];
                const float4 Y0 = Yr[0], Y1 = Yr[1], Y2 = Yr[2], Y3 = Yr[3];
#pragma unroll
                for (int c = 0; c < 4; ++c) {
                    const int j = (k >> 1) * 4 + c;
                    if (j >= j0 + 16) {
                        const float4* Br = (const float4*)&Pb[(j - j0) * PSTR];
                        vv[j] -= dot16(Y0, Y1, Y2, Y3, Br[0], Br[1], Br[2], Br[3]);
                    } else if (j >= j0) {
                        vv[j] = Pb[(128 + rr) * PSTR + (j - j0)];  // solved y copyback
                    }
                }
                if (jb < 7) {
                    float* Pn = P[(jb + 1) & 1];
#pragma unroll
                    for (int c = 0; c < 4; ++c) {
                        const int j = (k >> 1) * 4 + c;
                        if (j >= j0 + 16 && j < j0 + 32)
                            Pn[(128 + rr) * PSTR + (j - j0 - 16)] = vv[j];
                    }
                }
            }
        }
        __syncthreads();                                   // B6
        // ============== backward solve (L^T x = y) on wave 0 ==============
        float b00 = 0.0f, b01 = 0.0f, b10 = 0.0f, b11 = 0.0f;
        if (wave == 0) {
            b00 = v0[lane]; b01 = v0[lane + 64];
            b10 = v1[lane]; b11 = v1[lane + 64];
        }
#pragma unroll 1
        for (int jb = 7; jb >= 0; --jb) {
            const int j0 = 16 * jb;
            float* Pb = P[jb & 1];
            if (i >= j0 && i < j0 + 16) {   // stage 16 L-rows (both halves)
                float4* dst = (float4*)&Pb[(i - j0) * BSTR + 64 * h];
#pragma unroll
                for (int s = 0; s < 16; ++s) dst[s] = R[s];
            }
            __syncthreads();                               // B7
            if (wave == 0) {
#pragma unroll
                for (int c2 = 15; c2 >= 0; --c2) {
                    const int c = j0 + c2;
                    const float di = dinv[c];
                    const float s0 = (c < 64) ? b00 : b01;
                    const float s1 = (c < 64) ? b10 : b11;
                    const float x0 = __shfl(s0, c & 63) * di;
                    const float x1 = __shfl(s1, c & 63) * di;
                    const float L0 = Pb[c2 * BSTR + lane];
                    const float L1 = Pb[c2 * BSTR + lane + 64];
                    const int r0 = lane, r1 = lane + 64;
                    if (r0 < c)       { b00 -= L0 * x0; b10 -= L0 * x1; }
                    else if (r0 == c) { b00 = x0;       b10 = x1; }
                    if (r1 < c)       { b01 -= L1 * x0; b11 -= L1 * x1; }
                    else if (r1 == c) { b01 = x0;       b11 = x1; }
                }
            }
        }
        // ---- dnu + step size on wave 0 ----
        if (wave == 0) {
            v0[lane] = b00; v0[lane + 64] = b01;
            v1[lane] = b10; v1[lane + 64] = b11;
            float s0 = b00 + b01, s1 = b10 + b11;
#pragma unroll
            for (int o = 32; o; o >>= 1) { s0 += __shfl_xor(s0, o); s1 += __shfl_xor(s1, o); }
            const float dnu = (s0 + scal[2]) / s1;
            float r = 3.4e38f;
            const float a0 = av[lane], a1 = av[lane + 64];
            const float lm0 = lamv[lane], lm1 = lamv[lane + 64];
            const float da0 = b00 - dnu * b10;
            const float da1 = b01 - dnu * b11;
            const float dl0 = -lm0 + SIGMA_C * mu / a0 - lm0 * da0 / a0;
            const float dl1 = -lm1 + SIGMA_C * mu / a1 - lm1 * da1 / a1;
            if (da0 < 0.0f) r = fminf(r, -a0 / da0);
            if (da1 < 0.0f) r = fminf(r, -a1 / da1);
            if (dl0 < 0.0f) r = fminf(r, -lm0 / dl0);
            if (dl1 < 0.0f) r = fminf(r, -lm1 / dl1);
#pragma unroll
            for (int o = 32; o; o >>= 1) r = fminf(r, __shfl_xor(r, o));
            if (lane == 0) { scal[3] = dnu; scal[4] = fminf(1.0f, 0.99f * r); }
        }
        __syncthreads();                                   // B8
        // ---- update ----
        {
            const float ts   = scal[4];
            const float dnu2 = scal[3];
            if (t < N) {
                const float ai = av[t], li = lamv[t];
                const float dai = v0[t] - dnu2 * v1[t];
                const float dli = -li + SIGMA_C * mu / ai - li * dai / ai;
                av[t]   = ai + ts * dai;
                lamv[t] = li + ts * dli;
            }
            if (t == 0) scal[0] = nu + ts * dnu2;
        }
        __syncthreads();                                   // B9
    }

    if (t < N) alphas[(size_t)b * N + t] = av[t];
}

// ---------------- Kernel C: centers = alpha^T X ----------------
__global__ __launch_bounds__(256) void centers_kernel(const float* __restrict__ X,
                                                      const float* __restrict__ alphas,
                                                      float* __restrict__ out) {
    const int b = blockIdx.x;
    __shared__ float al[N];
    const int t = threadIdx.x;
    if (t < N) al[t] = alphas[(size_t)b * N + t];
    __syncthreads();
    const float* Xb = X + (size_t)b * N * DDIM;
    float acc0 = 0.0f, acc1 = 0.0f, acc2 = 0.0f, acc3 = 0.0f;
    for (int s = 0; s < N; ++s) {
        const float a = al[s];
        const float* row = Xb + (size_t)s * DDIM + t;
        acc0 += a * row[0];
        acc1 += a * row[256];
        acc2 += a * row[512];
        acc3 += a * row[768];
    }
    float* ob = out + (size_t)b * DDIM + t;
    ob[0]   = acc0;
    ob[256] = acc1;
    ob[512] = acc2;
    ob[768] = acc3;
}

extern "C" void kernel_launch(void* const* d_in, const int* in_sizes, int n_in,
                              void* d_out, int out_size, void* d_ws, size_t ws_size,
                              hipStream_t stream) {
    (void)in_sizes; (void)n_in; (void)out_size; (void)ws_size;
    const float* X = (const float*)d_in[0];
    float* out = (float*)d_out;
    float* Q = (float*)d_ws;                       // 512*128*128 f32 = 32 MB
    float* alphas = Q + (size_t)BATCH * N * N;     // + 256 KB
    gram_kernel<<<dim3(BATCH), dim3(256), 0, stream>>>(X, Q);
    ipm_kernel<<<dim3(BATCH), dim3(256), 0, stream>>>(Q, alphas);
    centers_kernel<<<dim3(BATCH), dim3(256), 0, stream>>>(X, alphas, out);
}

// Round 5
// 3537.098 us; speedup vs baseline: 1.9923x; 1.5850x over previous
//
#include <hip/hip_runtime.h>
#include <math.h>

#define BATCH   512
#define N       128
#define DDIM    1024
#define NITER   30
#define SIGMA_C 0.1f
#define EPS_C   1e-6f
#define LDM     132   // M row stride: (r*132+c)>>2 %32 = (r*33+(c>>2))%32 -> column reads spread all banks
#define MPAD    132

// ---------------- Kernel A: Q = 2*(X X^T + eps I) ----------------
__global__ __launch_bounds__(256) void gram_kernel(const float* __restrict__ X,
                                                   float* __restrict__ Q) {
    const int b = blockIdx.x;
    const float* Xb = X + (size_t)b * N * DDIM;
    float* Qb = Q + (size_t)b * N * N;

    __shared__ float Xs[16][MPAD];
    const int t  = threadIdx.x;
    const int tx = t & 15, ty = t >> 4;
    const int li = t >> 1;
    const int lk = (t & 1) * 8;

    float acc[8][8];
#pragma unroll
    for (int u = 0; u < 8; ++u)
#pragma unroll
        for (int v = 0; v < 8; ++v) acc[u][v] = 0.0f;

    for (int k0 = 0; k0 < DDIM; k0 += 16) {
        const float4 p0 = *(const float4*)(Xb + (size_t)li * DDIM + k0 + lk);
        const float4 p1 = *(const float4*)(Xb + (size_t)li * DDIM + k0 + lk + 4);
        __syncthreads();
        Xs[lk + 0][li] = p0.x; Xs[lk + 1][li] = p0.y;
        Xs[lk + 2][li] = p0.z; Xs[lk + 3][li] = p0.w;
        Xs[lk + 4][li] = p1.x; Xs[lk + 5][li] = p1.y;
        Xs[lk + 6][li] = p1.z; Xs[lk + 7][li] = p1.w;
        __syncthreads();
#pragma unroll
        for (int kk = 0; kk < 16; ++kk) {
            float4 A0 = *(const float4*)&Xs[kk][ty * 8];
            float4 A1 = *(const float4*)&Xs[kk][ty * 8 + 4];
            float4 C0 = *(const float4*)&Xs[kk][tx * 8];
            float4 C1 = *(const float4*)&Xs[kk][tx * 8 + 4];
            float a[8] = {A0.x, A0.y, A0.z, A0.w, A1.x, A1.y, A1.z, A1.w};
            float c[8] = {C0.x, C0.y, C0.z, C0.w, C1.x, C1.y, C1.z, C1.w};
#pragma unroll
            for (int u = 0; u < 8; ++u)
#pragma unroll
                for (int v = 0; v < 8; ++v) acc[u][v] += a[u] * c[v];
        }
    }
#pragma unroll
    for (int u = 0; u < 8; ++u) {
        const int i = ty * 8 + u;
#pragma unroll
        for (int v = 0; v < 8; ++v) {
            const int k = tx * 8 + v;
            acc[u][v] = 2.0f * acc[u][v] + ((i == k) ? 2.0f * EPS_C : 0.0f);
        }
        float4 o0, o1;
        o0.x = acc[u][0]; o0.y = acc[u][1]; o0.z = acc[u][2]; o0.w = acc[u][3];
        o1.x = acc[u][4]; o1.y = acc[u][5]; o1.z = acc[u][6]; o1.w = acc[u][7];
        *(float4*)(Qb + (size_t)i * N + tx * 8)     = o0;
        *(float4*)(Qb + (size_t)i * N + tx * 8 + 4) = o1;
    }
}

// ---------------- Kernel B: one WAVE per batch item ----------------
// 64 threads/block, 512 blocks (2 blocks/CU, LDS-bound). No inter-wave
// choreography: the wave owns the whole 130x132 augmented matrix in LDS.
// Q loaded ONCE; each iteration restores the lower triangle from the
// untouched upper triangle (Cholesky writes lower only; diag-factor
// writeback masked to c<=r). RHS = rows 128/129 (forward solve fused).
__global__ __launch_bounds__(64) void ipm_wave(const float* __restrict__ Q,
                                               float* __restrict__ alphas) {
    const int b = blockIdx.x;
    const float* Qb = Q + (size_t)b * N * N;

    __shared__ __align__(16) float M[130 * LDM];
    __shared__ __align__(16) float av[N], lam[N], dinv[N];

    const int l  = threadIdx.x;
    const int r0 = l, r1 = l + 64;

    // one-time Q load (coalesced float4)
#pragma unroll
    for (int p = 0; p < 64; ++p) {
        const int f   = (p << 6) + l;       // float4 id 0..4095
        const int row = f >> 5;
        const int c4  = (f & 31) << 2;
        *(float4*)&M[row * LDM + c4] = *(const float4*)(Qb + (size_t)row * N + c4);
    }
    av[r0] = 1.0f / 128.0f; av[r1] = 1.0f / 128.0f;
    lam[r0] = 1.0f;         lam[r1] = 1.0f;
    __syncthreads();
    const float qd0 = M[r0 * LDM + r0];
    const float qd1 = M[r1 * LDM + r1];
    const float pp0 = -0.5f * qd0, pp1 = -0.5f * qd1;
    float nu = 0.0f;

#pragma unroll 1
    for (int iter = 0; iter < NITER; ++iter) {
        // ---- restore lower triangle from upper (iter>0) ----
        if (iter > 0) {
#pragma unroll 1
            for (int r = 1; r < 128; ++r) {
                if (l < r)  M[r * LDM + l]  = M[l  * LDM + r];
                if (r1 < r) M[r * LDM + r1] = M[r1 * LDM + r];
            }
            M[r0 * LDM + r0] = qd0;
            M[r1 * LDM + r1] = qd1;
            __syncthreads();
        }
        // ---- qa = Q @ a (rows r0, r1; original diagonal in place) ----
        float qa0 = 0.0f, qa1 = 0.0f;
#pragma unroll
        for (int j4 = 0; j4 < 128; j4 += 4) {
            const float4 a4 = *(const float4*)&av[j4];
            const float4 m0 = *(const float4*)&M[r0 * LDM + j4];
            const float4 m1 = *(const float4*)&M[r1 * LDM + j4];
            qa0 = fmaf(m0.x, a4.x, qa0); qa0 = fmaf(m0.y, a4.y, qa0);
            qa0 = fmaf(m0.z, a4.z, qa0); qa0 = fmaf(m0.w, a4.w, qa0);
            qa1 = fmaf(m1.x, a4.x, qa1); qa1 = fmaf(m1.y, a4.y, qa1);
            qa1 = fmaf(m1.z, a4.z, qa1); qa1 = fmaf(m1.w, a4.w, qa1);
        }
        const float a0v = av[r0], a1v = av[r1];
        const float lm0 = lam[r0], lm1 = lam[r1];
        float sa  = a0v + a1v;
        float sal = a0v * lm0 + a1v * lm1;
#pragma unroll
        for (int o = 32; o; o >>= 1) { sa += __shfl_xor(sa, o); sal += __shfl_xor(sal, o); }
        const float r_pri = sa - 1.0f;
        const float mu = sal * (1.0f / 128.0f);
        // rhs rows + diag shift
        M[128 * LDM + r0] = -(qa0 + pp0 + nu - SIGMA_C * mu / a0v);
        M[128 * LDM + r1] = -(qa1 + pp1 + nu - SIGMA_C * mu / a1v);
        M[129 * LDM + r0] = 1.0f;
        M[129 * LDM + r1] = 1.0f;
        M[r0 * LDM + r0] = qd0 + lm0 / a0v;
        M[r1 * LDM + r1] = qd1 + lm1 / a1v;
        __syncthreads();

        // ============ blocked Cholesky, NB=16, 8 panels ============
#pragma unroll 1
        for (int jb = 0; jb < 8; ++jb) {
            const int j0 = jb * 16;
            // (a) diag block factor: register + shfl, lanes 0..15
            {
                float row[16];
                float myri = 0.0f;
                if (l < 16) {
#pragma unroll
                    for (int c = 0; c < 16; ++c) row[c] = M[(j0 + l) * LDM + j0 + c];
                } else {
#pragma unroll
                    for (int c = 0; c < 16; ++c) row[c] = 1.0f;
                }
#pragma unroll
                for (int c = 0; c < 16; ++c) {
                    const float d  = __shfl(row[c], c);
                    const float ri = rsqrtf(d);
                    if (l == c) { row[c] = d * ri; myri = ri; }
                    const float lv = (l > c && l < 16) ? row[c] * ri : 0.0f;
                    if (l > c && l < 16) row[c] = lv;
#pragma unroll
                    for (int k = c + 1; k < 16; ++k) row[k] -= lv * __shfl(lv, k);
                }
                if (l < 16) {
#pragma unroll
                    for (int c = 0; c < 16; ++c)
                        if (c <= l) M[(j0 + l) * LDM + j0 + c] = row[c];  // lower only: keep upper = Q
                    dinv[j0 + l] = myri;
                }
            }
            __syncthreads();
            // (b) panel solve: rows j0+16..129 (incl. rhs rows), <=2 per lane
            {
                const int cnt = 114 - 16 * jb;
                const int i1 = j0 + 16 + l;
                const int i2 = i1 + 64;
                const bool act1 = (l < cnt), act2 = (l + 64 < cnt);
                const int ri1 = act1 ? i1 : (j0 + 16);
                const int ri2 = act2 ? i2 : (j0 + 16);
                float w1[16], w2[16];
#pragma unroll
                for (int c4 = 0; c4 < 16; c4 += 4) {
                    *(float4*)&w1[c4] = *(const float4*)&M[ri1 * LDM + j0 + c4];
                    *(float4*)&w2[c4] = *(const float4*)&M[ri2 * LDM + j0 + c4];
                }
#pragma unroll
                for (int c = 0; c < 16; ++c) {
                    float s1 = w1[c], s2 = w2[c];
#pragma unroll
                    for (int m = 0; m < c; ++m) {
                        const float Lcm = M[(j0 + c) * LDM + j0 + m];
                        s1 -= w1[m] * Lcm;
                        s2 -= w2[m] * Lcm;
                    }
                    const float di = dinv[j0 + c];
                    w1[c] = s1 * di;
                    w2[c] = s2 * di;
                }
                if (act1) {
#pragma unroll
                    for (int c4 = 0; c4 < 16; c4 += 4)
                        *(float4*)&M[i1 * LDM + j0 + c4] = *(const float4*)&w1[c4];
                }
                if (act2) {
#pragma unroll
                    for (int c4 = 0; c4 < 16; c4 += 4)
                        *(float4*)&M[i2 * LDM + j0 + c4] = *(const float4*)&w2[c4];
                }
            }
            __syncthreads();
            // (c) rhs trailing: rows 128/129 vs cols j0+16..127
            if (jb < 7) {
                float y0[16], y1[16];
#pragma unroll
                for (int c4 = 0; c4 < 16; c4 += 4) {
                    *(float4*)&y0[c4] = *(const float4*)&M[128 * LDM + j0 + c4];
                    *(float4*)&y1[c4] = *(const float4*)&M[129 * LDM + j0 + c4];
                }
#pragma unroll 1
                for (int rep = 0; rep < 2; ++rep) {
                    const int j = j0 + 16 + l + rep * 64;
                    if (j < 128) {
                        float s0 = 0.0f, s1 = 0.0f;
#pragma unroll
                        for (int m4 = 0; m4 < 16; m4 += 4) {
                            const float4 Lj = *(const float4*)&M[j * LDM + j0 + m4];
                            s0 = fmaf(Lj.x, y0[m4 + 0], s0); s0 = fmaf(Lj.y, y0[m4 + 1], s0);
                            s0 = fmaf(Lj.z, y0[m4 + 2], s0); s0 = fmaf(Lj.w, y0[m4 + 3], s0);
                            s1 = fmaf(Lj.x, y1[m4 + 0], s1); s1 = fmaf(Lj.y, y1[m4 + 1], s1);
                            s1 = fmaf(Lj.z, y1[m4 + 2], s1); s1 = fmaf(Lj.w, y1[m4 + 3], s1);
                        }
                        M[128 * LDM + j] -= s0;
                        M[129 * LDM + j] -= s1;
                    }
                }
            }
            // (d) trailing SYRK: 64x16 tiles, lane = 4 rows x 4 cols
            {
                const int rg = l >> 2;   // 0..15
                const int cg = l & 3;    // 0..3
#pragma unroll 1
                for (int R0 = j0 + 16; R0 < 128; R0 += 64) {
                    const int i0 = R0 + rg * 4;
#pragma unroll 1
                    for (int C0 = j0 + 16; C0 < 128; C0 += 16) {
                        if (C0 > R0 + 63) break;
                        const int jc0 = C0 + cg * 4;
                        float acc[4][4];
#pragma unroll
                        for (int u = 0; u < 4; ++u)
#pragma unroll
                            for (int v = 0; v < 4; ++v) acc[u][v] = 0.0f;
#pragma unroll
                        for (int m4 = 0; m4 < 16; m4 += 4) {
                            float4 A[4], Bv[4];
#pragma unroll
                            for (int u = 0; u < 4; ++u) {
                                const int ia = (i0 + u) < 128 ? (i0 + u) : 127;
                                A[u] = *(const float4*)&M[ia * LDM + j0 + m4];
                            }
#pragma unroll
                            for (int v = 0; v < 4; ++v)
                                Bv[v] = *(const float4*)&M[(jc0 + v) * LDM + j0 + m4];
#pragma unroll
                            for (int u = 0; u < 4; ++u)
#pragma unroll
                                for (int v = 0; v < 4; ++v) {
                                    acc[u][v] = fmaf(A[u].x, Bv[v].x, acc[u][v]);
                                    acc[u][v] = fmaf(A[u].y, Bv[v].y, acc[u][v]);
                                    acc[u][v] = fmaf(A[u].z, Bv[v].z, acc[u][v]);
                                    acc[u][v] = fmaf(A[u].w, Bv[v].w, acc[u][v]);
                                }
                        }
#pragma unroll
                        for (int u = 0; u < 4; ++u) {
                            const int i = i0 + u;
                            if (i < 128) {
                                if (jc0 + 3 <= i) {
                                    float4 cc = *(const float4*)&M[i * LDM + jc0];
                                    cc.x -= acc[u][0]; cc.y -= acc[u][1];
                                    cc.z -= acc[u][2]; cc.w -= acc[u][3];
                                    *(float4*)&M[i * LDM + jc0] = cc;
                                } else {
#pragma unroll
                                    for (int v = 0; v < 4; ++v)
                                        if (jc0 + v <= i) M[i * LDM + jc0 + v] -= acc[u][v];
                                }
                            }
                        }
                    }
                }
            }
            __syncthreads();
        }

        // ============ backward solve (L^T x = y), in-register ============
        float x00 = M[128 * LDM + r0], x01 = M[128 * LDM + r1];
        float x10 = M[129 * LDM + r0], x11 = M[129 * LDM + r1];
#pragma unroll 1
        for (int c = 127; c >= 0; --c) {
            const float di = dinv[c];
            const float s0 = (c < 64) ? x00 : x01;
            const float s1 = (c < 64) ? x10 : x11;
            const float xc0 = __shfl(s0, c & 63) * di;
            const float xc1 = __shfl(s1, c & 63) * di;
            const float L0 = M[c * LDM + r0];
            const float L1 = M[c * LDM + r1];
            if (r0 < c)       { x00 -= L0 * xc0; x10 -= L0 * xc1; }
            else if (r0 == c) { x00 = xc0;       x10 = xc1; }
            if (r1 < c)       { x01 -= L1 * xc0; x11 -= L1 * xc1; }
            else if (r1 == c) { x01 = xc0;       x11 = xc1; }
        }
        // ---- dnu, step, update (all in registers) ----
        float t0 = x00 + x01, t1 = x10 + x11;
#pragma unroll
        for (int o = 32; o; o >>= 1) { t0 += __shfl_xor(t0, o); t1 += __shfl_xor(t1, o); }
        const float dnu = (t0 + r_pri) / t1;
        const float da0 = x00 - dnu * x10;
        const float da1 = x01 - dnu * x11;
        const float dl0 = -lm0 + SIGMA_C * mu / a0v - lm0 * da0 / a0v;
        const float dl1 = -lm1 + SIGMA_C * mu / a1v - lm1 * da1 / a1v;
        float rstep = 3.4e38f;
        if (da0 < 0.0f) rstep = fminf(rstep, -a0v / da0);
        if (da1 < 0.0f) rstep = fminf(rstep, -a1v / da1);
        if (dl0 < 0.0f) rstep = fminf(rstep, -lm0 / dl0);
        if (dl1 < 0.0f) rstep = fminf(rstep, -lm1 / dl1);
#pragma unroll
        for (int o = 32; o; o >>= 1) rstep = fminf(rstep, __shfl_xor(rstep, o));
        const float ts = fminf(1.0f, 0.99f * rstep);
        av[r0]  = a0v + ts * da0;
        av[r1]  = a1v + ts * da1;
        lam[r0] = lm0 + ts * dl0;
        lam[r1] = lm1 + ts * dl1;
        nu += ts * dnu;
        __syncthreads();
    }

    alphas[(size_t)b * N + r0] = av[r0];
    alphas[(size_t)b * N + r1] = av[r1];
}

// ---------------- Kernel C: centers = alpha^T X ----------------
__global__ __launch_bounds__(256) void centers_kernel(const float* __restrict__ X,
                                                      const float* __restrict__ alphas,
                                                      float* __restrict__ out) {
    const int b = blockIdx.x;
    __shared__ float al[N];
    const int t = threadIdx.x;
    if (t < N) al[t] = alphas[(size_t)b * N + t];
    __syncthreads();
    const float* Xb = X + (size_t)b * N * DDIM;
    float acc0 = 0.0f, acc1 = 0.0f, acc2 = 0.0f, acc3 = 0.0f;
    for (int s = 0; s < N; ++s) {
        const float a = al[s];
        const float* row = Xb + (size_t)s * DDIM + t;
        acc0 += a * row[0];
        acc1 += a * row[256];
        acc2 += a * row[512];
        acc3 += a * row[768];
    }
    float* ob = out + (size_t)b * DDIM + t;
    ob[0]   = acc0;
    ob[256] = acc1;
    ob[512] = acc2;
    ob[768] = acc3;
}

extern "C" void kernel_launch(void* const* d_in, const int* in_sizes, int n_in,
                              void* d_out, int out_size, void* d_ws, size_t ws_size,
                              hipStream_t stream) {
    (void)in_sizes; (void)n_in; (void)out_size; (void)ws_size;
    const float* X = (const float*)d_in[0];
    float* out = (float*)d_out;
    float* Q = (float*)d_ws;                       // 512*128*128 f32 = 32 MB
    float* alphas = Q + (size_t)BATCH * N * N;     // + 256 KB
    gram_kernel<<<dim3(BATCH), dim3(256), 0, stream>>>(X, Q);
    ipm_wave<<<dim3(BATCH), dim3(64), 0, stream>>>(Q, alphas);
    centers_kernel<<<dim3(BATCH), dim3(256), 0, stream>>>(X, alphas, out);
}

// Round 6
// 2874.481 us; speedup vs baseline: 2.4516x; 1.2305x over previous
//
#include <hip/hip_runtime.h>
#include <math.h>

#define BATCH   512
#define N       128
#define DDIM    1024
#define NITER   30
#define SIGMA_C 0.1f
#define EPS_C   1e-6f
#define MPAD    132
#define BSTRIDE 264   // floats per 16x16 block: 264 % 32 = 8 -> per-block bank rotation

// packed lower-triangle block id (bi >= bj)
__device__ __forceinline__ int blkid(int bi, int bj) { return ((bi * (bi + 1)) >> 1) + bj; }
// float offset of element (rin, cin) inside block blk, with f4-slot XOR swizzle
__device__ __forceinline__ int eoff(int blk, int rin, int cin) {
    return blk * BSTRIDE + rin * 16 + ((((cin >> 2) ^ (rin >> 2)) & 3) << 2) + (cin & 3);
}
// float4 offset for slot s (= cin>>2)
__device__ __forceinline__ int f4off(int blk, int rin, int s) {
    return blk * 66 + rin * 4 + ((s ^ (rin >> 2)) & 3);
}

// ---------------- Kernel A: Q = 2*(X X^T + eps I) ----------------
__global__ __launch_bounds__(256) void gram_kernel(const float* __restrict__ X,
                                                   float* __restrict__ Q) {
    const int b = blockIdx.x;
    const float* Xb = X + (size_t)b * N * DDIM;
    float* Qb = Q + (size_t)b * N * N;

    __shared__ float Xs[16][MPAD];
    const int t  = threadIdx.x;
    const int tx = t & 15, ty = t >> 4;
    const int li = t >> 1;
    const int lk = (t & 1) * 8;

    float acc[8][8];
#pragma unroll
    for (int u = 0; u < 8; ++u)
#pragma unroll
        for (int v = 0; v < 8; ++v) acc[u][v] = 0.0f;

    for (int k0 = 0; k0 < DDIM; k0 += 16) {
        const float4 p0 = *(const float4*)(Xb + (size_t)li * DDIM + k0 + lk);
        const float4 p1 = *(const float4*)(Xb + (size_t)li * DDIM + k0 + lk + 4);
        __syncthreads();
        Xs[lk + 0][li] = p0.x; Xs[lk + 1][li] = p0.y;
        Xs[lk + 2][li] = p0.z; Xs[lk + 3][li] = p0.w;
        Xs[lk + 4][li] = p1.x; Xs[lk + 5][li] = p1.y;
        Xs[lk + 6][li] = p1.z; Xs[lk + 7][li] = p1.w;
        __syncthreads();
#pragma unroll
        for (int kk = 0; kk < 16; ++kk) {
            float4 A0 = *(const float4*)&Xs[kk][ty * 8];
            float4 A1 = *(const float4*)&Xs[kk][ty * 8 + 4];
            float4 C0 = *(const float4*)&Xs[kk][tx * 8];
            float4 C1 = *(const float4*)&Xs[kk][tx * 8 + 4];
            float a[8] = {A0.x, A0.y, A0.z, A0.w, A1.x, A1.y, A1.z, A1.w};
            float c[8] = {C0.x, C0.y, C0.z, C0.w, C1.x, C1.y, C1.z, C1.w};
#pragma unroll
            for (int u = 0; u < 8; ++u)
#pragma unroll
                for (int v = 0; v < 8; ++v) acc[u][v] += a[u] * c[v];
        }
    }
#pragma unroll
    for (int u = 0; u < 8; ++u) {
        const int i = ty * 8 + u;
#pragma unroll
        for (int v = 0; v < 8; ++v) {
            const int k = tx * 8 + v;
            acc[u][v] = 2.0f * acc[u][v] + ((i == k) ? 2.0f * EPS_C : 0.0f);
        }
        float4 o0, o1;
        o0.x = acc[u][0]; o0.y = acc[u][1]; o0.z = acc[u][2]; o0.w = acc[u][3];
        o1.x = acc[u][4]; o1.y = acc[u][5]; o1.z = acc[u][6]; o1.w = acc[u][7];
        *(float4*)(Qb + (size_t)i * N + tx * 8)     = o0;
        *(float4*)(Qb + (size_t)i * N + tx * 8 + 4) = o1;
    }
}

// ---------------- Kernel B: IPM, 2 items / block, 2 waves / item ----------------
// Packed lower-triangle (36 blocks of 16x16, swizzled) in LDS; Q reloaded from
// global (L2/L3-resident) each iteration -- no restore phase. Wave0: diag factor;
// wave1 (concurrent): rhs forward-trailing of previous panel. SYRK split by tile
// parity. Backward solves for rhs0/rhs1 run on separate waves concurrently.
__global__ __launch_bounds__(256) void ipm_duo(const float* __restrict__ Q,
                                               float* __restrict__ alphas) {
    __shared__ __align__(16) float Msh[2][36 * BSTRIDE];
    __shared__ __align__(16) float avs[2][128], lams[2][128], dinvs[2][128];
    __shared__ __align__(16) float r0s[2][128], r1s[2][128];
    __shared__ float scals[2][8];

    const int t    = threadIdx.x;
    const int h    = t >> 7;          // item half
    const int ti   = t & 127;         // thread within item
    const int wi   = (t >> 6) & 1;    // wave within item
    const int lane = t & 63;
    const int b    = (blockIdx.x << 1) + h;

    const float* Qb = Q + (size_t)b * N * N;
    float* M    = Msh[h];
    float* AV   = avs[h];
    float* LAM  = lams[h];
    float* DINV = dinvs[h];
    float* RH0  = r0s[h];
    float* RH1  = r1s[h];
    float* SC   = scals[h];

    AV[ti]  = 1.0f / 128.0f;
    LAM[ti] = 1.0f;
    if (ti == 0) { SC[0] = 0.5f; SC[1] = 0.5f; SC[2] = 0.5f; SC[3] = 0.5f; }
    float nu = 0.0f;
    __syncthreads();

#pragma unroll 1
    for (int iter = 0; iter < NITER; ++iter) {
        // ---------- reload lower-triangle blocks from global ----------
        for (int p = 0; p < 18; ++p) {
            const int f4  = ti + (p << 7);          // 0..2303
            const int blk = f4 >> 6;
            int bi = (int)(0.5f * (sqrtf(8.0f * (float)blk + 1.0f) - 1.0f));
            if ((((bi + 1) * (bi + 2)) >> 1) <= blk) ++bi;
            if (((bi * (bi + 1)) >> 1) > blk) --bi;
            const int bj  = blk - ((bi * (bi + 1)) >> 1);
            const int rin = (f4 >> 2) & 15;
            const int sl  = f4 & 3;
            const float4 val = *(const float4*)(Qb + (size_t)(bi * 16 + rin) * N + bj * 16 + (sl << 2));
            ((float4*)M)[f4off(blk, rin, sl)] = val;
        }
        __syncthreads();                                       // B1
        const float r_pri = SC[0] + SC[1] - 1.0f;
        const float mu    = (SC[2] + SC[3]) * (1.0f / 128.0f);
        // ---------- qa = Q@a, rhs build, diag shift ----------
        {
            const int r = ti, rb = r >> 4, ri = r & 15;
            float qa = 0.0f;
#pragma unroll
            for (int bb = 0; bb < 8; ++bb) {
                if (bb <= rb) {                    // row read from block (rb, bb)
                    const int bq = blkid(rb, bb);
                    const float* ab = &AV[bb << 4];
#pragma unroll
                    for (int sl = 0; sl < 4; ++sl) {
                        const float4 m4 = ((const float4*)M)[f4off(bq, ri, sl)];
                        const float4 a4 = *(const float4*)&ab[sl << 2];
                        qa = fmaf(m4.x, a4.x, qa); qa = fmaf(m4.y, a4.y, qa);
                        qa = fmaf(m4.z, a4.z, qa); qa = fmaf(m4.w, a4.w, qa);
                    }
                } else {                           // column read from block (bb, rb)
                    const int bq = blkid(bb, rb);
                    const float* ab = &AV[bb << 4];
#pragma unroll
                    for (int k = 0; k < 16; ++k)
                        qa = fmaf(M[eoff(bq, k, ri)], ab[k], qa);
                }
            }
            const float ai = AV[r], li = LAM[r];
            const int dix  = eoff(blkid(rb, rb), ri, ri);
            const float qd = M[dix];
            RH0[r] = -(qa - 0.5f * qd + nu - SIGMA_C * mu / ai);
            RH1[r] = 1.0f;
            M[dix] = qd + li / ai;
        }
        __syncthreads();                                       // B2

        // ---------- 8 panels ----------
#pragma unroll 1
        for (int jb = 0; jb < 8; ++jb) {
            const int j0 = jb << 4;
            // phase A: wave0 diag factor ; wave1 rhs-trailing of panel jb-1
            if (wi == 0) {
                const int dblk = blkid(jb, jb);
                float row[16];
                float myri = 0.0f;
                if (lane < 16) {
#pragma unroll
                    for (int c = 0; c < 16; ++c) row[c] = M[eoff(dblk, lane, c)];
                } else {
#pragma unroll
                    for (int c = 0; c < 16; ++c) row[c] = 1.0f;
                }
#pragma unroll
                for (int c = 0; c < 16; ++c) {
                    const float d   = __shfl(row[c], c);
                    const float riv = rsqrtf(d);
                    if (lane == c) { row[c] = d * riv; myri = riv; }
                    const float lv = (lane > c && lane < 16) ? row[c] * riv : 0.0f;
                    if (lane > c && lane < 16) row[c] = lv;
#pragma unroll
                    for (int k = c + 1; k < 16; ++k) row[k] -= lv * __shfl(lv, k);
                }
                if (lane < 16) {
#pragma unroll
                    for (int c = 0; c < 16; ++c)
                        if (c <= lane) M[eoff(dblk, lane, c)] = row[c];
                    DINV[j0 + lane] = myri;
                }
            } else if (jb > 0) {
                const int jp = j0 - 16;
                float y0[16], y1[16];
#pragma unroll
                for (int m = 0; m < 16; ++m) { y0[m] = RH0[jp + m]; y1[m] = RH1[jp + m]; }
#pragma unroll
                for (int rep = 0; rep < 2; ++rep) {
                    const int j = j0 + lane + (rep << 6);
                    if (j < 128) {
                        const int lb = blkid(j >> 4, jb - 1);
                        const int jr = j & 15;
                        float s0 = 0.0f, s1 = 0.0f;
#pragma unroll
                        for (int m = 0; m < 16; ++m) {
                            const float lv = M[eoff(lb, jr, m)];
                            s0 = fmaf(lv, y0[m], s0);
                            s1 = fmaf(lv, y1[m], s1);
                        }
                        RH0[j] -= s0; RH1[j] -= s1;
                    }
                }
            }
            __syncthreads();                                   // Ba
            // phase B: TRSM, one row per thread (+2 rhs rows)
            {
                const int cnt = 112 - j0;
                if (ti < cnt + 2) {
                    const bool mrow = (ti < cnt);
                    const int i  = j0 + 16 + ti;
                    const int ib = mrow ? blkid(i >> 4, jb) : 0;
                    const int ir = i & 15;
                    float w[16];
                    if (mrow) {
#pragma unroll
                        for (int sl = 0; sl < 4; ++sl)
                            *(float4*)&w[sl << 2] = ((const float4*)M)[f4off(ib, ir, sl)];
                    } else {
                        const float* rp = (ti == cnt) ? RH0 : RH1;
#pragma unroll
                        for (int c = 0; c < 16; ++c) w[c] = rp[j0 + c];
                    }
                    const int dblk = blkid(jb, jb);
#pragma unroll
                    for (int c = 0; c < 16; ++c) {
                        float sv = w[c];
#pragma unroll
                        for (int m = 0; m < c; ++m) sv -= w[m] * M[eoff(dblk, c, m)];
                        w[c] = sv * DINV[j0 + c];
                    }
                    if (mrow) {
#pragma unroll
                        for (int sl = 0; sl < 4; ++sl)
                            ((float4*)M)[f4off(ib, ir, sl)] = *(const float4*)&w[sl << 2];
                    } else {
                        float* rp = (ti == cnt) ? RH0 : RH1;
#pragma unroll
                        for (int c = 0; c < 16; ++c) rp[j0 + c] = w[c];
                    }
                }
            }
            __syncthreads();                                   // Bb
            // phase C: trailing SYRK (tiles 64x16, parity-split across waves)
            if (jb < 7) {
                const int rg = lane >> 2, cg = lane & 3;
                int tc = 0;
#pragma unroll 1
                for (int R0 = j0 + 16; R0 < 128; R0 += 64) {
                    const int i0 = R0 + (rg << 2);
                    int cmax = R0 + 63; if (cmax > 112) cmax = 112;
#pragma unroll 1
                    for (int C0 = j0 + 16; C0 <= cmax; C0 += 16) {
                        if (((tc++) & 1) != wi) continue;
                        if (i0 >= 128) continue;
                        const int rin = i0 & 15;
                        const int bA  = blkid(i0 >> 4, jb);
                        const int bj  = C0 >> 4;
                        const int bB  = blkid(bj, jb);
                        const int bC  = blkid(i0 >> 4, bj);
                        float acc[4][4];
#pragma unroll
                        for (int u = 0; u < 4; ++u)
#pragma unroll
                            for (int v = 0; v < 4; ++v) acc[u][v] = 0.0f;
#pragma unroll
                        for (int m4 = 0; m4 < 4; ++m4) {
                            float4 A[4], B[4];
#pragma unroll
                            for (int u = 0; u < 4; ++u)
                                A[u] = ((const float4*)M)[f4off(bA, rin + u, m4)];
#pragma unroll
                            for (int v = 0; v < 4; ++v)
                                B[v] = ((const float4*)M)[f4off(bB, (cg << 2) + v, m4)];
#pragma unroll
                            for (int u = 0; u < 4; ++u)
#pragma unroll
                                for (int v = 0; v < 4; ++v) {
                                    acc[u][v] = fmaf(A[u].x, B[v].x, acc[u][v]);
                                    acc[u][v] = fmaf(A[u].y, B[v].y, acc[u][v]);
                                    acc[u][v] = fmaf(A[u].z, B[v].z, acc[u][v]);
                                    acc[u][v] = fmaf(A[u].w, B[v].w, acc[u][v]);
                                }
                        }
                        if ((i0 >> 4) > bj) {                  // strictly-below block: full f4 rmw
#pragma unroll
                            for (int u = 0; u < 4; ++u) {
                                const int ix = f4off(bC, rin + u, cg);
                                float4 cc = ((const float4*)M)[ix];
                                cc.x -= acc[u][0]; cc.y -= acc[u][1];
                                cc.z -= acc[u][2]; cc.w -= acc[u][3];
                                ((float4*)M)[ix] = cc;
                            }
                        } else {                               // diagonal block: mask c <= i
#pragma unroll
                            for (int u = 0; u < 4; ++u) {
                                const int i = i0 + u;
#pragma unroll
                                for (int v = 0; v < 4; ++v) {
                                    const int c = C0 + (cg << 2) + v;
                                    if (c <= i) M[eoff(bC, rin + u, (cg << 2) + v)] -= acc[u][v];
                                }
                            }
                        }
                    }
                }
                __syncthreads();                               // Bc
            }
        }

        // ---------- backward solves: wave wi owns rhs_wi (concurrent) ----------
        {
            float* rp = (wi == 0) ? RH0 : RH1;
            float xlo = rp[lane], xhi = rp[lane + 64];
            const int rbl = lane >> 4, rbh = (lane + 64) >> 4;
            const int rcl = lane & 15;
#pragma unroll 1
            for (int c = 127; c >= 0; --c) {
                const float s  = (c < 64) ? xlo : xhi;
                const float xc = __shfl(s, c & 63) * DINV[c];
                const int cb = c >> 4, ci = c & 15;
                if (lane < c)            xlo -= M[eoff(blkid(cb, rbl), ci, rcl)] * xc;
                else if (lane == c)      xlo  = xc;
                if (lane + 64 < c)       xhi -= M[eoff(blkid(cb, rbh), ci, rcl)] * xc;
                else if (lane + 64 == c) xhi  = xc;
            }
            rp[lane] = xlo; rp[lane + 64] = xhi;
            float ss = xlo + xhi;
#pragma unroll
            for (int o = 32; o; o >>= 1) ss += __shfl_xor(ss, o);
            if (lane == 0) SC[4 + wi] = ss;
        }
        __syncthreads();                                       // B5
        // ---------- dnu + step candidates ----------
        const float dnu = (SC[4] + r_pri) / SC[5];
        {
            const float x0 = RH0[ti], x1 = RH1[ti];
            const float ai = AV[ti], li = LAM[ti];
            const float da = x0 - dnu * x1;
            const float dl = -li + SIGMA_C * mu / ai - li * da / ai;
            float rr = 3.4e38f;
            if (da < 0.0f) rr = fminf(rr, -ai / da);
            if (dl < 0.0f) rr = fminf(rr, -li / dl);
#pragma unroll
            for (int o = 32; o; o >>= 1) rr = fminf(rr, __shfl_xor(rr, o));
            if (lane == 0) SC[6 + wi] = rr;
            RH0[ti] = da; RH1[ti] = dl;
        }
        __syncthreads();                                       // B6
        // ---------- apply step + stats for next iteration ----------
        {
            const float ts = fminf(1.0f, 0.99f * fminf(SC[6], SC[7]));
            const float na = AV[ti] + ts * RH0[ti];
            const float nl = LAM[ti] + ts * RH1[ti];
            AV[ti] = na; LAM[ti] = nl;
            nu += ts * dnu;
            float sa = na, sal = na * nl;
#pragma unroll
            for (int o = 32; o; o >>= 1) { sa += __shfl_xor(sa, o); sal += __shfl_xor(sal, o); }
            if (lane == 0) { SC[0 + wi] = sa; SC[2 + wi] = sal; }
        }
        // next-iteration B1 orders these writes before their readers
    }
    __syncthreads();
    alphas[(size_t)b * N + ti] = AV[ti];
}

// ---------------- Kernel C: centers = alpha^T X ----------------
__global__ __launch_bounds__(256) void centers_kernel(const float* __restrict__ X,
                                                      const float* __restrict__ alphas,
                                                      float* __restrict__ out) {
    const int b = blockIdx.x;
    __shared__ float al[N];
    const int t = threadIdx.x;
    if (t < N) al[t] = alphas[(size_t)b * N + t];
    __syncthreads();
    const float* Xb = X + (size_t)b * N * DDIM;
    float acc0 = 0.0f, acc1 = 0.0f, acc2 = 0.0f, acc3 = 0.0f;
    for (int s = 0; s < N; ++s) {
        const float a = al[s];
        const float* row = Xb + (size_t)s * DDIM + t;
        acc0 += a * row[0];
        acc1 += a * row[256];
        acc2 += a * row[512];
        acc3 += a * row[768];
    }
    float* ob = out + (size_t)b * DDIM + t;
    ob[0]   = acc0;
    ob[256] = acc1;
    ob[512] = acc2;
    ob[768] = acc3;
}

extern "C" void kernel_launch(void* const* d_in, const int* in_sizes, int n_in,
                              void* d_out, int out_size, void* d_ws, size_t ws_size,
                              hipStream_t stream) {
    (void)in_sizes; (void)n_in; (void)out_size; (void)ws_size;
    const float* X = (const float*)d_in[0];
    float* out = (float*)d_out;
    float* Q = (float*)d_ws;                       // 512*128*128 f32 = 32 MB
    float* alphas = Q + (size_t)BATCH * N * N;     // + 256 KB
    gram_kernel<<<dim3(BATCH), dim3(256), 0, stream>>>(X, Q);
    ipm_duo<<<dim3(BATCH / 2), dim3(256), 0, stream>>>(Q, alphas);
    centers_kernel<<<dim3(BATCH), dim3(256), 0, stream>>>(X, alphas, out);
}